// Round 9
// baseline (114.643 us; speedup 1.0000x reference)
//
#include <hip/hip_runtime.h>
#include <cstdint>
#include <cstddef>

#define BB 512
#define TT 8192
#define TW 256          // u32 spike words per row-channel (TT/32)
#define KWIN 5

static __device__ __forceinline__ float fract_f(float x) {
#if __has_builtin(__builtin_amdgcn_fractf)
    return __builtin_amdgcn_fractf(x);
#else
    return x - floorf(x);
#endif
}

// ---------------------------------------------------------------------------
// Kernel 1: segmented LIF scan, REGISTER-RESIDENT (no LDS at all).
// 1536 blocks x 64 threads = one wave per (batch row, channel).
// Lane l loads its OWN keep window x[128l .. 128l+128) as 32 float4 directly
// global->VGPR (512-B stride between lanes; each 64-B sector is reused by 4
// consecutive loads of the same lane -> L1 absorbs, net HBM = row read once).
// Warm-up input for lane l is lane (l-1)'s keep window -> __shfl_up(x,1)
// per step (lane 0 forced to x=0: t<0 has no input, v stays 0 exactly).
// Shfl operands are chain-independent -> off the critical path.
// No LDS => no residency cap: all 6 waves/CU co-resident in ONE round
// (VGPR ~160 < 256, launch_bounds(64,2)); ~12.3k cyc/CU VALU-bound.
// Warm-up contraction: v' = fract(0.7 v + x) contracts circle-distance by
// 0.7/step => 128 discarded steps collapse the state bit-exactly (validated
// rounds 6-8: absmax 0.3339844 = one spike flip in 12.6M, topk indices
// exact, 20x threshold margin). Chain math UNFUSED mul+add (numpy's two
// roundings) + exact v_fract — identical op sequence => identical spikes.
// ---------------------------------------------------------------------------
__global__ __launch_bounds__(64, 2)
void lif_scan_kernel(const float* __restrict__ amp,
                     const float* __restrict__ pitch,
                     const float* __restrict__ boundary,
                     const float* __restrict__ decay,
                     float* __restrict__ out)
{
    const int blk = blockIdx.x;          // 0..1535
    const int c   = blk >> 9;            // channel
    const int b   = blk & 511;           // batch row
    const int l   = threadIdx.x;         // 0..63
    const float* __restrict__ src =
        (c == 0 ? amp : (c == 1 ? pitch : boundary)) + (size_t)b * TT;
    const float dv = decay[c];

    // lane's keep window: float4s [32l .. 32l+32)
    const float4* __restrict__ w4 = reinterpret_cast<const float4*>(src) + 32 * l;
    float4 W[32];
#pragma unroll
    for (int i = 0; i < 32; ++i) W[i] = w4[i];

    float v = 0.0f;

    // ---- warm-up: 128 discarded steps on lane (l-1)'s window via shfl ----
    const bool z = (l == 0);
#define WSTEP(xx)                                               \
    {                                                           \
        float xw = __shfl_up((xx), 1);                          \
        if (z) xw = 0.0f;                                       \
        float t2 = __fadd_rn(__fmul_rn(dv, v), xw);             \
        v = fract_f(t2);                                        \
    }
#pragma unroll
    for (int i = 0; i < 32; ++i) {
        WSTEP(W[i].x) WSTEP(W[i].y) WSTEP(W[i].z) WSTEP(W[i].w)
    }
#undef WSTEP

    // ---- keep: 128 exact steps, spike bits from own registers ----
    uint32_t w[4];
    float bs;
#define KSTEP(xx)                                               \
    {                                                           \
        float t2 = __fadd_rn(__fmul_rn(dv, v), (xx));           \
        float nv = fract_f(t2);                                 \
        bs = __builtin_fmaf(2.0f, bs, t2 - nv);                 \
        v = nv;                                                 \
    }
#pragma unroll
    for (int q = 0; q < 4; ++q) {
        bs = 0.0f;
#pragma unroll
        for (int i = 8 * q; i < 8 * q + 4; ++i) {
            KSTEP(W[i].x) KSTEP(W[i].y) KSTEP(W[i].z) KSTEP(W[i].w)
        }
        const uint32_t hi = (uint32_t)bs;
        bs = 0.0f;
#pragma unroll
        for (int i = 8 * q + 4; i < 8 * q + 8; ++i) {
            KSTEP(W[i].x) KSTEP(W[i].y) KSTEP(W[i].z) KSTEP(W[i].w)
        }
        w[q] = (hi << 16) | (uint32_t)bs;
    }
#undef KSTEP

    // spike words: row b's sal head region, channel c's 256 words, lane l's 4
    uint32_t* wout = reinterpret_cast<uint32_t*>(out + 512 + (size_t)b * TT)
                   + c * TW;
    *reinterpret_cast<uint4*>(wout + 4 * l) = make_uint4(w[0], w[1], w[2], w[3]);
}

// ---------------------------------------------------------------------------
// Kernel 2: per-row normalize + top-k (512 blocks x 256 threads) — verbatim
// from rounds 5-8 (validated):
//   sal has only 8 possible values (w . s). Presence bitmask -> denom;
//   ONE IEEE divide per table entry (bitwise == numpy elementwise divide).
//   Streaming per-thread top-5 (5 u64 regs), then 5 block-max rounds.
//   Key = mono(val)<<32 | (8191-t)  => value desc, index asc (lax.top_k).
// ---------------------------------------------------------------------------
__global__ __launch_bounds__(256, 2)
void salience_topk_kernel(const float* __restrict__ weights,
                          float* __restrict__ out)
{
    const int b = blockIdx.x;
    const int tid = threadIdx.x;

    __shared__ uint32_t words[3 * TW];
    __shared__ uint32_t spres[4];
    __shared__ float ntab[8];
    __shared__ uint32_t htab[8];
    __shared__ unsigned long long red[4];
    __shared__ unsigned long long wins;

    float* sal_out = out + 512 + (size_t)b * TT;
    const uint32_t* wsrc = reinterpret_cast<const uint32_t*>(sal_out);

    words[tid]       = wsrc[tid];
    words[tid + 256] = wsrc[tid + 256];
    words[tid + 512] = wsrc[tid + 512];

    const float w0 = weights[0], w1 = weights[1], w2 = weights[2];
    __syncthreads();

    uint32_t pres = 0;
#pragma unroll
    for (int j = 0; j < 8; ++j) {
        const int t0 = 4 * tid + 1024 * j;
        const int wi = t0 >> 5;
        const uint32_t wa = words[wi], wp = words[TW + wi], wq = words[2 * TW + wi];
#pragma unroll
        for (int k = 0; k < 4; ++k) {
            const int sh = 31 - ((t0 & 31) + k);
            const uint32_t idx = ((wa >> sh) & 1u)
                               | (((wp >> sh) & 1u) << 1)
                               | (((wq >> sh) & 1u) << 2);
            pres |= (1u << idx);
        }
    }
#pragma unroll
    for (int off = 32; off; off >>= 1)
        pres |= __shfl_down(pres, off);
    if ((tid & 63) == 0) spres[tid >> 6] = pres;
    __syncthreads();

    if (tid < 8) {
        const uint32_t p = spres[0] | spres[1] | spres[2] | spres[3];
        float s0 = (float)(tid & 1), s1 = (float)((tid >> 1) & 1), s2 = (float)(tid >> 2);
        float tv = __fadd_rn(__fadd_rn(__fmul_rn(w0, s0), __fmul_rn(w1, s1)),
                             __fmul_rn(w2, s2));
        float m = ((p >> tid) & 1u) ? tv : -INFINITY;
        m = fmaxf(m, __shfl_xor(m, 1));
        m = fmaxf(m, __shfl_xor(m, 2));
        m = fmaxf(m, __shfl_xor(m, 4));
        const float denom = __fadd_rn(m, 1e-6f);
        float nv = tv / denom;
        ntab[tid] = nv;
        uint32_t ub = __float_as_uint(nv);
        htab[tid] = (ub & 0x80000000u) ? ~ub : (ub | 0x80000000u);
    }
    __syncthreads();

    unsigned long long t5[5] = {0ull, 0ull, 0ull, 0ull, 0ull};
#pragma unroll
    for (int j = 0; j < 8; ++j) {
        const int t0 = 4 * tid + 1024 * j;
        const int wi = t0 >> 5;
        const uint32_t wa = words[wi], wp = words[TW + wi], wq = words[2 * TW + wi];
        float4 q;
        float* qp = &q.x;
#pragma unroll
        for (int k = 0; k < 4; ++k) {
            const int sh = 31 - ((t0 & 31) + k);
            const uint32_t idx = ((wa >> sh) & 1u)
                               | (((wp >> sh) & 1u) << 1)
                               | (((wq >> sh) & 1u) << 2);
            qp[k] = ntab[idx];
            unsigned long long key = ((unsigned long long)htab[idx] << 32)
                                   | (unsigned long long)(uint32_t)(TT - 1 - (t0 + k));
            if (key > t5[4]) {
#pragma unroll
                for (int i = 0; i < 5; ++i) {
                    bool g = key > t5[i];
                    unsigned long long o = t5[i];
                    t5[i] = g ? key : o;
                    key   = g ? o : key;
                }
            }
        }
        *reinterpret_cast<float4*>(sal_out + t0) = q;
    }

    float vsum = 0.0f;
    for (int r = 0; r < KWIN; ++r) {
        unsigned long long cand = t5[0];
#pragma unroll
        for (int off = 32; off; off >>= 1) {
            unsigned long long o = __shfl_down(cand, off);
            if (o > cand) cand = o;
        }
        __syncthreads();
        if ((tid & 63) == 0) red[tid >> 6] = cand;
        __syncthreads();
        if (tid == 0) {
            unsigned long long m = red[0];
            if (red[1] > m) m = red[1];
            if (red[2] > m) m = red[2];
            if (red[3] > m) m = red[3];
            wins = m;
        }
        __syncthreads();
        const unsigned long long w = wins;
        if (t5[0] == w) {
            t5[0] = t5[1]; t5[1] = t5[2]; t5[2] = t5[3]; t5[3] = t5[4]; t5[4] = 0ull;
        }
        if (tid == 0) {
            uint32_t hi = (uint32_t)(w >> 32);
            uint32_t fb = (hi & 0x80000000u) ? (hi & 0x7FFFFFFFu) : ~hi;
            vsum += __uint_as_float(fb);
            out[512 + (size_t)BB * TT + (size_t)b * KWIN + r] =
                (float)(int)(TT - 1 - (uint32_t)(w & 0xFFFFFFFFull));
        }
    }

    if (tid == 0) {
        out[b] = 0.5f + 2.0f * tanhf(1.8f * (vsum / 5.0f));
    }
}

extern "C" void kernel_launch(void* const* d_in, const int* in_sizes, int n_in,
                              void* d_out, int out_size, void* d_ws, size_t ws_size,
                              hipStream_t stream) {
    const float* amp      = (const float*)d_in[0];
    const float* pitch    = (const float*)d_in[1];
    const float* boundary = (const float*)d_in[2];
    const float* decay    = (const float*)d_in[3];
    const float* weights  = (const float*)d_in[4];
    float* out = (float*)d_out;

    lif_scan_kernel<<<3 * BB, 64, 0, stream>>>(amp, pitch, boundary, decay, out);
    salience_topk_kernel<<<BB, 256, 0, stream>>>(weights, out);
}

// Round 10
// 111.777 us; speedup vs baseline: 1.0256x; 1.0256x over previous
//
#include <hip/hip_runtime.h>
#include <cstdint>
#include <cstddef>

#define BB 512
#define TT 8192
#define TW 256          // u32 spike words per row-channel (TT/32)
#define KWIN 5

static __device__ __forceinline__ float fract_f(float x) {
#if __has_builtin(__builtin_amdgcn_fractf)
    return __builtin_amdgcn_fractf(x);
#else
    return x - floorf(x);
#endif
}

// ---------------------------------------------------------------------------
// ONE fused kernel: 512 blocks (one per batch row) x 256 threads (4 waves).
//
// Scan phase (waves 0..2, wave = channel): register-resident segmented LIF
// scan, verbatim round-9 math (validated absmax 0.3339844, topk exact):
//   lane l loads its keep window x[128l..128l+128) as 32 float4 global->VGPR;
//   warm-up = 128 discarded steps on lane (l-1)'s window via __shfl_up
//   (lane 0 forced x=0); v'=fract(0.7v+x) contracts 0.7/step => state
//   collapses bit-exactly after 128 steps. Keep = 128 exact steps, UNFUSED
//   mul+add (numpy's two roundings) + exact v_fract. Spike words -> LDS
//   (3 KB) — never to global (they were overwritten anyway). Wave 3 idles.
//
// Topk phase (all 256 threads, after ONE barrier): verbatim rounds 5-9
// validated logic: presence bitmask -> denom; ONE IEEE divide per 8-entry
// table value (bitwise == numpy elementwise divide); coalesced float4 sal
// stores; streaming per-thread top-5 (u64 keys: mono(val)<<32 | (8191-t)
// => value desc, index asc = lax.top_k); 5 block-max rounds; tanh epilogue.
//
// Why fused: rounds 7-9 showed the total is insensitive to scan structure —
// either the kernels are already tiny (reset-floor-dominated) or something
// invisible is slow. Fusing removes a launch + the spike-word global
// round-trip AND makes the single kernel big enough to surface in the top-5
// profile if it exceeds the 42-us ws-poison fills — diagnostic either way.
// Register budget: W[32]=128 VGPRs (scan) dies before topk temps; ~160 peak,
// fits 2 waves/SIMD (launch_bounds(256,2)) -> 2 blocks/CU co-resident.
// ---------------------------------------------------------------------------
__global__ __launch_bounds__(256, 2)
void fused_spike_topk_kernel(const float* __restrict__ amp,
                             const float* __restrict__ pitch,
                             const float* __restrict__ boundary,
                             const float* __restrict__ decay,
                             const float* __restrict__ weights,
                             float* __restrict__ out)
{
    const int b    = blockIdx.x;         // batch row
    const int tid  = threadIdx.x;        // 0..255
    const int wave = tid >> 6;           // 0..3
    const int l    = tid & 63;           // lane in wave

    __shared__ uint32_t words[3 * TW];   // 3 KB spike words
    __shared__ uint32_t spres[4];
    __shared__ float ntab[8];
    __shared__ uint32_t htab[8];
    __shared__ unsigned long long red[4];
    __shared__ unsigned long long wins;

    // ---------------- scan phase: waves 0..2, one channel each ------------
    if (wave < 3) {
        const int c = wave;
        const float* __restrict__ src =
            (c == 0 ? amp : (c == 1 ? pitch : boundary)) + (size_t)b * TT;
        const float dv = decay[c];

        // lane's keep window: float4s [32l .. 32l+32)
        const float4* __restrict__ w4 =
            reinterpret_cast<const float4*>(src) + 32 * l;
        float4 W[32];
#pragma unroll
        for (int i = 0; i < 32; ++i) W[i] = w4[i];

        float v = 0.0f;

        // warm-up: 128 discarded steps on lane (l-1)'s window via shfl
        const bool z = (l == 0);
#define WSTEP(xx)                                               \
        {                                                       \
            float xw = __shfl_up((xx), 1);                      \
            if (z) xw = 0.0f;                                   \
            float t2 = __fadd_rn(__fmul_rn(dv, v), xw);         \
            v = fract_f(t2);                                    \
        }
#pragma unroll
        for (int i = 0; i < 32; ++i) {
            WSTEP(W[i].x) WSTEP(W[i].y) WSTEP(W[i].z) WSTEP(W[i].w)
        }
#undef WSTEP

        // keep: 128 exact steps, spike bits (MSB-first per 32-step word)
        uint32_t w[4];
        float bs;
#define KSTEP(xx)                                               \
        {                                                       \
            float t2 = __fadd_rn(__fmul_rn(dv, v), (xx));       \
            float nv = fract_f(t2);                             \
            bs = __builtin_fmaf(2.0f, bs, t2 - nv);             \
            v = nv;                                             \
        }
#pragma unroll
        for (int q = 0; q < 4; ++q) {
            bs = 0.0f;
#pragma unroll
            for (int i = 8 * q; i < 8 * q + 4; ++i) {
                KSTEP(W[i].x) KSTEP(W[i].y) KSTEP(W[i].z) KSTEP(W[i].w)
            }
            const uint32_t hi = (uint32_t)bs;
            bs = 0.0f;
#pragma unroll
            for (int i = 8 * q + 4; i < 8 * q + 8; ++i) {
                KSTEP(W[i].x) KSTEP(W[i].y) KSTEP(W[i].z) KSTEP(W[i].w)
            }
            w[q] = (hi << 16) | (uint32_t)bs;
        }
#undef KSTEP

        // spike words straight to LDS (16B-aligned uint4)
        *reinterpret_cast<uint4*>(&words[c * TW + 4 * l]) =
            make_uint4(w[0], w[1], w[2], w[3]);
    }

    const float w0 = weights[0], w1 = weights[1], w2 = weights[2];
    __syncthreads();                     // spikes visible to all 4 waves

    // ---------------- topk phase: all 256 threads -------------------------
    uint32_t pres = 0;
#pragma unroll
    for (int j = 0; j < 8; ++j) {
        const int t0 = 4 * tid + 1024 * j;
        const int wi = t0 >> 5;
        const uint32_t wa = words[wi], wp = words[TW + wi], wq = words[2 * TW + wi];
#pragma unroll
        for (int k = 0; k < 4; ++k) {
            const int sh = 31 - ((t0 & 31) + k);
            const uint32_t idx = ((wa >> sh) & 1u)
                               | (((wp >> sh) & 1u) << 1)
                               | (((wq >> sh) & 1u) << 2);
            pres |= (1u << idx);
        }
    }
#pragma unroll
    for (int off = 32; off; off >>= 1)
        pres |= __shfl_down(pres, off);
    if ((tid & 63) == 0) spres[tid >> 6] = pres;
    __syncthreads();

    if (tid < 8) {
        const uint32_t p = spres[0] | spres[1] | spres[2] | spres[3];
        float s0 = (float)(tid & 1), s1 = (float)((tid >> 1) & 1), s2 = (float)(tid >> 2);
        float tv = __fadd_rn(__fadd_rn(__fmul_rn(w0, s0), __fmul_rn(w1, s1)),
                             __fmul_rn(w2, s2));
        float m = ((p >> tid) & 1u) ? tv : -INFINITY;
        m = fmaxf(m, __shfl_xor(m, 1));
        m = fmaxf(m, __shfl_xor(m, 2));
        m = fmaxf(m, __shfl_xor(m, 4));
        const float denom = __fadd_rn(m, 1e-6f);
        float nv = tv / denom;           // exact IEEE div, once per value
        ntab[tid] = nv;
        uint32_t ub = __float_as_uint(nv);
        htab[tid] = (ub & 0x80000000u) ? ~ub : (ub | 0x80000000u);
    }
    __syncthreads();

    float* sal_out = out + 512 + (size_t)b * TT;
    unsigned long long t5[5] = {0ull, 0ull, 0ull, 0ull, 0ull};
#pragma unroll
    for (int j = 0; j < 8; ++j) {
        const int t0 = 4 * tid + 1024 * j;
        const int wi = t0 >> 5;
        const uint32_t wa = words[wi], wp = words[TW + wi], wq = words[2 * TW + wi];
        float4 q;
        float* qp = &q.x;
#pragma unroll
        for (int k = 0; k < 4; ++k) {
            const int sh = 31 - ((t0 & 31) + k);
            const uint32_t idx = ((wa >> sh) & 1u)
                               | (((wp >> sh) & 1u) << 1)
                               | (((wq >> sh) & 1u) << 2);
            qp[k] = ntab[idx];
            unsigned long long key = ((unsigned long long)htab[idx] << 32)
                                   | (unsigned long long)(uint32_t)(TT - 1 - (t0 + k));
            if (key > t5[4]) {
#pragma unroll
                for (int i = 0; i < 5; ++i) {
                    bool g = key > t5[i];
                    unsigned long long o = t5[i];
                    t5[i] = g ? key : o;
                    key   = g ? o : key;
                }
            }
        }
        *reinterpret_cast<float4*>(sal_out + t0) = q;
    }

    float vsum = 0.0f;
    for (int r = 0; r < KWIN; ++r) {
        unsigned long long cand = t5[0];
#pragma unroll
        for (int off = 32; off; off >>= 1) {
            unsigned long long o = __shfl_down(cand, off);
            if (o > cand) cand = o;
        }
        __syncthreads();
        if ((tid & 63) == 0) red[tid >> 6] = cand;
        __syncthreads();
        if (tid == 0) {
            unsigned long long m = red[0];
            if (red[1] > m) m = red[1];
            if (red[2] > m) m = red[2];
            if (red[3] > m) m = red[3];
            wins = m;
        }
        __syncthreads();
        const unsigned long long w = wins;
        if (t5[0] == w) {                // unique key -> one thread retires
            t5[0] = t5[1]; t5[1] = t5[2]; t5[2] = t5[3]; t5[3] = t5[4]; t5[4] = 0ull;
        }
        if (tid == 0) {
            uint32_t hi = (uint32_t)(w >> 32);
            uint32_t fb = (hi & 0x80000000u) ? (hi & 0x7FFFFFFFu) : ~hi;
            vsum += __uint_as_float(fb);
            out[512 + (size_t)BB * TT + (size_t)b * KWIN + r] =
                (float)(int)(TT - 1 - (uint32_t)(w & 0xFFFFFFFFull));
        }
    }

    if (tid == 0) {
        out[b] = 0.5f + 2.0f * tanhf(1.8f * (vsum / 5.0f));
    }
}

extern "C" void kernel_launch(void* const* d_in, const int* in_sizes, int n_in,
                              void* d_out, int out_size, void* d_ws, size_t ws_size,
                              hipStream_t stream) {
    const float* amp      = (const float*)d_in[0];
    const float* pitch    = (const float*)d_in[1];
    const float* boundary = (const float*)d_in[2];
    const float* decay    = (const float*)d_in[3];
    const float* weights  = (const float*)d_in[4];
    float* out = (float*)d_out;

    fused_spike_topk_kernel<<<BB, 256, 0, stream>>>(amp, pitch, boundary,
                                                    decay, weights, out);
}